// Round 5
// baseline (123.448 us; speedup 1.0000x reference)
//
#include <hip/hip_runtime.h>

typedef float f4 __attribute__((ext_vector_type(4)));

#define BB   16
#define NN   512
#define DIN  256
#define COUT 32
#define CCS  48
#define HH   256
#define WWG  256
#define HW   (HH * WWG)          // 65536 = 1<<16
#define CTOT (CCS + COUT)        // 80

#define NGEMM   1024             // BB*NN/8 GEMM blocks
#define NWIN    1                // 1 winner block
#define NFILL   (BB * CTOT * 8)  // 10240 fill blocks (8 chunks per channel-image)
#define FILL0   (NGEMM + NWIN)

// ---------------------------------------------------------------------------
// One fused, LDS-FREE kernel (8 blocks/CU):
//  blocks [0,1024):   proj = emb·W + b. W read through L1 (32 KB, L1-resident);
//                     4-way split accumulator breaks the FMA dep chain.
//  block  1024:       winner map: write -1 to touched cells, __syncthreads,
//                     then atomicMax of flat entity index (max == last-write).
//  blocks [1025,...): fill — copy 48 spatial channels, zero 32 scatter
//                     channels. 8 f4/thread, nontemporal, branch-free.
// ---------------------------------------------------------------------------
__global__ __launch_bounds__(256) void k_fused(
        const float* __restrict__ emb, const float* __restrict__ Wm,
        const float* __restrict__ bias, const int* __restrict__ loc,
        const float* __restrict__ sp,
        float* __restrict__ proj, int* __restrict__ winner,
        float* __restrict__ out) {
    int tid = threadIdx.x;
    int bx  = blockIdx.x;

    if (bx < NGEMM) {
        // ---- proj GEMM (no LDS) ----
        int c = tid & 31;
        int r = tid >> 5;                        // 0..7
        int row = bx * 8 + r;                    // flat entity index, 0..8191
        const f4* e4 = (const f4*)(emb + (size_t)row * DIN);
        const float* wc = Wm + c;
        float a0 = 0.f, a1 = 0.f, a2 = 0.f, a3 = 0.f;
        #pragma unroll 8
        for (int d4 = 0; d4 < DIN / 4; ++d4) {
            f4 ev = e4[d4];
            int d = d4 * 4;
            a0 += ev.x * wc[(size_t)(d + 0) * COUT];
            a1 += ev.y * wc[(size_t)(d + 1) * COUT];
            a2 += ev.z * wc[(size_t)(d + 2) * COUT];
            a3 += ev.w * wc[(size_t)(d + 3) * COUT];
        }
        proj[(size_t)row * COUT + c] = (a0 + a1) + (a2 + a3) + bias[c];
        return;
    }
    if (bx == NGEMM) {
        // ---- winner map (single block; only touched cells — replay-safe) ----
        #pragma unroll
        for (int k = 0; k < BB * NN / 256; ++k) {
            int i = k * 256 + tid;
            int b = i >> 9;
            int h = loc[2 * i + 0];
            int w = loc[2 * i + 1];
            winner[b * HW + h * WWG + w] = -1;
        }
        __syncthreads();
        #pragma unroll
        for (int k = 0; k < BB * NN / 256; ++k) {
            int i = k * 256 + tid;
            int b = i >> 9;
            int h = loc[2 * i + 0];
            int w = loc[2 * i + 1];
            atomicMax(&winner[b * HW + h * WWG + w], i);
        }
        return;
    }

    // ---- fill: one block = one 2048-f4 chunk of one (b, ch) image ----
    int fx    = bx - FILL0;                      // 0..10239
    int chunk = fx & 7;
    int rest  = fx >> 3;                         // 0..1279 (scalar regs)
    int ch    = rest % CTOT;
    int b     = rest / CTOT;
    f4* o = (f4*)out + (((size_t)(b * CTOT + ch) << 14) + chunk * 2048 + tid);
    if (ch < CCS) {
        const f4* s = (const f4*)sp + (((size_t)(b * CCS + ch) << 14) + chunk * 2048 + tid);
        f4 v[8];
        #pragma unroll
        for (int k = 0; k < 8; ++k) v[k] = __builtin_nontemporal_load(s + k * 256);
        #pragma unroll
        for (int k = 0; k < 8; ++k) __builtin_nontemporal_store(v[k], o + k * 256);
    } else {
        f4 z = (f4)(0.0f);
        #pragma unroll
        for (int k = 0; k < 8; ++k) __builtin_nontemporal_store(z, o + k * 256);
    }
}

// ---------------------------------------------------------------------------
// Winning entity writes its 32-channel proj vector to out[b, 48+c, h, w].
// ---------------------------------------------------------------------------
__global__ __launch_bounds__(256) void k_scatter(
        const float* __restrict__ proj, const int* __restrict__ loc,
        const int* __restrict__ winner, float* __restrict__ out) {
    int t = blockIdx.x * 256 + threadIdx.x;
    int c = t & 31;
    int i = t >> 5;                              // flat entity index
    int b = i >> 9;
    int h = loc[2 * i + 0];
    int w = loc[2 * i + 1];
    int cell = b * HW + h * WWG + w;
    if (winner[cell] != i) return;               // last-write-wins (max flat index)
    out[((size_t)(b * CTOT + CCS + c) << 16) + (size_t)h * WWG + w] =
        proj[(size_t)i * COUT + c];
}

extern "C" void kernel_launch(void* const* d_in, const int* in_sizes, int n_in,
                              void* d_out, int out_size, void* d_ws, size_t ws_size,
                              hipStream_t stream) {
    const float* sp   = (const float*)d_in[0];   // [16,48,256,256]
    const float* emb  = (const float*)d_in[1];   // [16,512,256]
    const float* Wm   = (const float*)d_in[2];   // [256,32]
    const float* bias = (const float*)d_in[3];   // [32]
    const int*   loc  = (const int*)d_in[4];     // [16,512,2]
    float* out = (float*)d_out;                  // [16,80,256,256]

    float* proj   = (float*)d_ws;                                     // 1 MB
    int*   winner = (int*)((char*)d_ws + (size_t)BB * NN * COUT * 4); // 4 MB

    hipLaunchKernelGGL(k_fused, dim3(NGEMM + NWIN + NFILL), dim3(256), 0, stream,
                       emb, Wm, bias, loc, sp, proj, winner, out);

    hipLaunchKernelGGL(k_scatter, dim3(BB * NN * COUT / 256), dim3(256), 0, stream,
                       proj, loc, winner, out);
}